// Round 5
// baseline (1444.136 us; speedup 1.0000x reference)
//
#include <hip/hip_runtime.h>

// Problem constants (fixed-size problem)
#define S_LEN 2048
#define HDIM  2048
#define NH    16
#define HD    128
#define MROWS 8192   // B*S

typedef __attribute__((ext_vector_type(8))) _Float16 half8;  // 8 x fp16 MFMA frag
typedef __attribute__((ext_vector_type(4))) float f32x4;     // MFMA accum

__device__ __forceinline__ _Float16 f2h(float f) { return (_Float16)f; }

// async global->LDS, 16B per lane. LDS dest must be wave-uniform base; HW adds lane*16.
__device__ __forceinline__ void gload16(const void* g, void* l) {
    __builtin_amdgcn_global_load_lds(
        (const __attribute__((address_space(1))) void*)g,
        (__attribute__((address_space(3))) void*)l,
        16, 0, 0);
}

// ---------------------------------------------------------------- prep kernels
__global__ void cast_x_kernel(const float* __restrict__ x, _Float16* __restrict__ xh) {
    size_t i = ((size_t)blockIdx.x * 256 + threadIdx.x) * 8;
    float4 a = *(const float4*)(x + i);
    float4 b = *(const float4*)(x + i + 4);
    half8 o;
    o[0]=f2h(a.x); o[1]=f2h(a.y); o[2]=f2h(a.z); o[3]=f2h(a.w);
    o[4]=f2h(b.x); o[5]=f2h(b.y); o[6]=f2h(b.z); o[7]=f2h(b.w);
    *(half8*)(xh + i) = o;
}

// All four weights in one launch: W [K][N] fp32 -> Wt [N][K] fp16. blockIdx.z picks weight.
__global__ void transpose_cast_w(const float* W0, const float* W1,
                                 const float* W2, const float* W3,
                                 _Float16* T0, _Float16* T1,
                                 _Float16* T2, _Float16* T3) {
    __shared__ float t[32][33];
    const float* W = (blockIdx.z == 0) ? W0 : (blockIdx.z == 1) ? W1 : (blockIdx.z == 2) ? W2 : W3;
    _Float16*   Wt = (blockIdx.z == 0) ? T0 : (blockIdx.z == 1) ? T1 : (blockIdx.z == 2) ? T2 : T3;
    int x0 = blockIdx.x * 32, y0 = blockIdx.y * 32;  // x: N, y: K
    int tx = threadIdx.x, ty = threadIdx.y;          // (32,8)
    #pragma unroll
    for (int i = 0; i < 32; i += 8)
        t[ty + i][tx] = W[(size_t)(y0 + ty + i) * HDIM + x0 + tx];
    __syncthreads();
    #pragma unroll
    for (int i = 0; i < 32; i += 8)
        Wt[(size_t)(x0 + ty + i) * HDIM + y0 + tx] = f2h(t[tx][ty + i]);
}

// Per-head transpose: Vn [bh][S][HD] fp16 -> Vt [bh][HD][S] fp16.
// fp16 [32][33] tile: row stride 66B puts even rows in banks 0..15, odd in 16..31 -> conflict-free.
__global__ void transpose_v(const _Float16* __restrict__ Vn, _Float16* __restrict__ Vt) {
    __shared__ _Float16 t[32][33];
    int d0 = blockIdx.x * 32, s0 = blockIdx.y * 32;
    size_t bh = blockIdx.z;
    const _Float16* src = Vn + bh * (size_t)S_LEN * HD;
    _Float16*       dst = Vt + bh * (size_t)S_LEN * HD;
    int tx = threadIdx.x, ty = threadIdx.y;          // (32,8)
    #pragma unroll
    for (int i = 0; i < 32; i += 8)
        t[ty + i][tx] = src[(size_t)(s0 + ty + i) * HD + d0 + tx];
    __syncthreads();
    #pragma unroll
    for (int i = 0; i < 32; i += 8)
        dst[(size_t)(d0 + ty + i) * S_LEN + s0 + tx] = t[tx][ty + i];
}

// ---------------------------------------------------------------- GEMM (m97 structure)
// C[M,N] = A[M,K](fp16) * Wt[N,K]^T(fp16) + bias, 128x128 tile, 4 waves (2x2), BK=32
// Grid is ALWAYS (64,16); T1 XCD swizzle assumes 1024 wgs (1024%8==0).
// MODE 0: write fp16 to [B][NH][S][HD]   (Q, K, V-natural)
// MODE 2: write fp32 to [M][N]           (final output)
template<int MODE>
__global__ __launch_bounds__(256, 2)
void gemm_kernel(const _Float16* __restrict__ A,
                 const _Float16* __restrict__ Bt,
                 const float* __restrict__ bias,
                 void* __restrict__ out,
                 int M, int N, int K)
{
    __shared__ _Float16 lA[128 * 32];
    __shared__ _Float16 lB[128 * 32];
    const int tid  = threadIdx.x;
    const int wave = tid >> 6;
    const int lane = tid & 63;
    const int fr = lane & 15, fq = lane >> 4;
    const int wr = wave >> 1, wc = wave & 1;

    // T1: XCD-aware bijective remap. XCD j gets tiles [j*128,(j+1)*128):
    // all 64 M-tiles for 2 consecutive n-columns -> B panel L2-resident.
    const int f  = blockIdx.x + blockIdx.y * 64;   // flat wg id (1024 total)
    const int t  = (f & 7) * 128 + (f >> 3);
    const size_t m0 = (size_t)(t & 63) * 128;
    const size_t n0 = (size_t)(t >> 6) * 128;

    f32x4 acc[4][4] = {};

    for (int kt = 0; kt < K; kt += 32) {
        #pragma unroll
        for (int c = 0; c < 2; ++c) {
            int off  = (c * 4 + wave) * 1024 + lane * 16; // byte offset in 8KB tile
            int row  = off >> 6;                          // 64B per row (32 fp16)
            int colb = off & 63;
            gload16((const char*)A  + ((m0 + row) * K + kt) * 2 + colb,
                    (char*)lA + (c * 4 + wave) * 1024);
            gload16((const char*)Bt + ((n0 + row) * K + kt) * 2 + colb,
                    (char*)lB + (c * 4 + wave) * 1024);
        }
        __syncthreads();
        half8 a_[4], b_[4];
        #pragma unroll
        for (int m = 0; m < 4; ++m)
            a_[m] = *(const half8*)&lA[(wr * 64 + m * 16 + fr) * 32 + fq * 8];
        #pragma unroll
        for (int n = 0; n < 4; ++n)
            b_[n] = *(const half8*)&lB[(wc * 64 + n * 16 + fr) * 32 + fq * 8];
        #pragma unroll
        for (int m = 0; m < 4; ++m)
            #pragma unroll
            for (int n = 0; n < 4; ++n)
                acc[m][n] = __builtin_amdgcn_mfma_f32_16x16x32_f16(a_[m], b_[n], acc[m][n], 0, 0, 0);
        __syncthreads();
    }

    #pragma unroll
    for (int m = 0; m < 4; ++m) {
        #pragma unroll
        for (int n = 0; n < 4; ++n) {
            #pragma unroll
            for (int r = 0; r < 4; ++r) {
                size_t row = m0 + wr * 64 + m * 16 + fq * 4 + r;   // token index
                size_t col = n0 + wc * 64 + n * 16 + fr;           // output feature
                float v = acc[m][n][r] + bias[col];
                if (MODE == 0) {
                    size_t b = row >> 11, s = row & 2047;
                    size_t h = col >> 7,  d = col & 127;
                    ((_Float16*)out)[((b * NH + h) * S_LEN + s) * HD + d] = f2h(v);
                } else {
                    ((float*)out)[row * (size_t)N + col] = v;
                }
            }
        }
    }
}

// ---------------------------------------------------------------- attention
// grid: (S/128, B*NH) = (16,64). 4 independent waves/block; each wave owns 32 Q rows.
// Q,K: [B][NH][S][HD] fp16; Vt: [B][NH][HD][S] fp16; O: [MROWS][HDIM] fp16.
__global__ __launch_bounds__(256, 2)
void attn_kernel(const _Float16* __restrict__ Q,
                 const _Float16* __restrict__ K,
                 const _Float16* __restrict__ Vt,
                 _Float16* __restrict__ O)
{
    __shared__ _Float16 p_lds[4 * 32 * 128];   // 8KB per wave, XOR-swizzled
    const int tid = threadIdx.x;
    const int wave = tid >> 6, lane = tid & 63;
    const int fr = lane & 15, fq = lane >> 4;

    // T1: XCD j gets heads [j*8,(j+1)*8), same-head q-blocks consecutive -> KV L2-resident.
    const int f  = blockIdx.x + blockIdx.y * 16;   // flat wg id (1024 total)
    const int t  = (f & 7) * 128 + (f >> 3);
    const int bh = t >> 4;                          // head-batch index
    const int q0 = (t & 15) * 128 + wave * 32;

    const _Float16* Qh = Q  + (size_t)bh * S_LEN * HD;
    const _Float16* Kh = K  + (size_t)bh * S_LEN * HD;
    const _Float16* Vh = Vt + (size_t)bh * HD * S_LEN;
    _Float16* pw = p_lds + wave * 32 * 128;

    // Q fragments resident in registers, pre-scaled by 1/sqrt(hd).
    const _Float16 hscale = (_Float16)0.08838834764831845f;  // 1/sqrt(128)
    half8 qf[2][4];
    #pragma unroll
    for (int m = 0; m < 2; ++m)
        #pragma unroll
        for (int kk = 0; kk < 4; ++kk) {
            half8 t_ = *(const half8*)&Qh[(size_t)(q0 + m * 16 + fr) * HD + kk * 32 + fq * 8];
            qf[m][kk] = t_ * hscale;
        }

    f32x4 acc_o[2][8] = {};
    float m_run[2][4], l_run[2][4];
    #pragma unroll
    for (int m = 0; m < 2; ++m)
        #pragma unroll
        for (int r = 0; r < 4; ++r) { m_run[m][r] = -1e30f; l_run[m][r] = 0.f; }

    for (int kt = 0; kt < S_LEN; kt += 128) {
        // ---- S = (Q/sqrt(hd)) K^T
        f32x4 acc_s[2][8] = {};
        #pragma unroll
        for (int kk = 0; kk < 4; ++kk) {
            half8 kf[8];
            #pragma unroll
            for (int n = 0; n < 8; ++n)
                kf[n] = *(const half8*)&Kh[(size_t)(kt + n * 16 + fr) * HD + kk * 32 + fq * 8];
            __builtin_amdgcn_s_setprio(1);
            #pragma unroll
            for (int m = 0; m < 2; ++m)
                #pragma unroll
                for (int n = 0; n < 8; ++n)
                    acc_s[m][n] = __builtin_amdgcn_mfma_f32_16x16x32_f16(qf[m][kk], kf[n], acc_s[m][n], 0, 0, 0);
            __builtin_amdgcn_s_setprio(0);
        }
        // ---- online softmax (rows fq*4+r; reduce over fr lanes + n regs)
        #pragma unroll
        for (int m = 0; m < 2; ++m) {
            #pragma unroll
            for (int r = 0; r < 4; ++r) {
                float rowmax = acc_s[m][0][r];
                #pragma unroll
                for (int n = 1; n < 8; ++n)
                    rowmax = fmaxf(rowmax, acc_s[m][n][r]);
                rowmax = fmaxf(rowmax, __shfl_xor(rowmax, 1));
                rowmax = fmaxf(rowmax, __shfl_xor(rowmax, 2));
                rowmax = fmaxf(rowmax, __shfl_xor(rowmax, 4));
                rowmax = fmaxf(rowmax, __shfl_xor(rowmax, 8));
                // T13 defer-max: only rescale when growth exceeds THR=8.
                float mold = m_run[m][r];
                if (rowmax > mold + 8.f) {
                    float fac = __expf(mold - rowmax);
                    m_run[m][r] = rowmax;
                    l_run[m][r] *= fac;
                    #pragma unroll
                    for (int n = 0; n < 8; ++n)
                        acc_o[m][n][r] *= fac;
                }
                float mcur = m_run[m][r];
                float rowsum = 0.f;
                #pragma unroll
                for (int n = 0; n < 8; ++n) {
                    float p = __expf(acc_s[m][n][r] - mcur);   // bounded by e^8
                    acc_s[m][n][r] = p;
                    rowsum += p;
                }
                rowsum += __shfl_xor(rowsum, 1);
                rowsum += __shfl_xor(rowsum, 2);
                rowsum += __shfl_xor(rowsum, 4);
                rowsum += __shfl_xor(rowsum, 8);
                l_run[m][r] += rowsum;
            }
        }
        // ---- P (D-layout) -> LDS, XOR-swizzled rows (256B row, swz bits 4-6)
        #pragma unroll
        for (int m = 0; m < 2; ++m)
            #pragma unroll
            for (int n = 0; n < 8; ++n)
                #pragma unroll
                for (int r = 0; r < 4; ++r) {
                    int row = m * 16 + fq * 4 + r;
                    int off = (row * 256 + (n * 16 + fr) * 2) ^ ((row & 7) << 4);
                    *(_Float16*)((char*)pw + off) = f2h(acc_s[m][n][r]);
                }
        asm volatile("s_waitcnt lgkmcnt(0)" ::: "memory");
        // ---- O += P V
        #pragma unroll
        for (int kk = 0; kk < 4; ++kk) {
            half8 pf[2], vf[8];
            #pragma unroll
            for (int m = 0; m < 2; ++m) {
                int row = m * 16 + fr;
                int off = (row * 256 + kk * 64 + fq * 16) ^ ((row & 7) << 4);
                pf[m] = *(const half8*)((const char*)pw + off);
            }
            #pragma unroll
            for (int n = 0; n < 8; ++n)
                vf[n] = *(const half8*)&Vh[(size_t)(n * 16 + fr) * S_LEN + kt + kk * 32 + fq * 8];
            __builtin_amdgcn_s_setprio(1);
            #pragma unroll
            for (int m = 0; m < 2; ++m)
                #pragma unroll
                for (int n = 0; n < 8; ++n)
                    acc_o[m][n] = __builtin_amdgcn_mfma_f32_16x16x32_f16(pf[m], vf[n], acc_o[m][n], 0, 0, 0);
            __builtin_amdgcn_s_setprio(0);
        }
    }

    // ---- epilogue: O / l, write fp16 [token][h*128+d]
    const int b = bh >> 4, h = bh & 15;
    #pragma unroll
    for (int m = 0; m < 2; ++m) {
        #pragma unroll
        for (int r = 0; r < 4; ++r) {
            float inv = 1.f / l_run[m][r];
            size_t tok = (size_t)b * S_LEN + q0 + m * 16 + fq * 4 + r;
            #pragma unroll
            for (int n = 0; n < 8; ++n) {
                size_t col = (size_t)h * HD + n * 16 + fr;
                O[tok * HDIM + col] = f2h(acc_o[m][n][r] * inv);
            }
        }
    }
}

// ---------------------------------------------------------------- launch
extern "C" void kernel_launch(void* const* d_in, const int* in_sizes, int n_in,
                              void* d_out, int out_size, void* d_ws, size_t ws_size,
                              hipStream_t stream)
{
    (void)in_sizes; (void)n_in; (void)out_size; (void)ws_size;
    const float* x  = (const float*)d_in[0];
    const float* Wq = (const float*)d_in[1];
    const float* bq = (const float*)d_in[2];
    const float* Wk = (const float*)d_in[3];
    const float* bk = (const float*)d_in[4];
    const float* Wv = (const float*)d_in[5];
    const float* bv = (const float*)d_in[6];
    const float* Wo = (const float*)d_in[7];
    const float* bo = (const float*)d_in[8];

    const size_t MB = 1024ull * 1024ull;
    char* ws = (char*)d_ws;
    // layout (needs 160MB of ws):
    _Float16* xh  = (_Float16*)(ws);            // 32MB: x fp16; reused as attn out
    _Float16* wqt = (_Float16*)(ws + 32 * MB);  // 8MB each
    _Float16* wkt = (_Float16*)(ws + 40 * MB);
    _Float16* wvt = (_Float16*)(ws + 48 * MB);
    _Float16* wot = (_Float16*)(ws + 56 * MB);
    _Float16* Qh  = (_Float16*)(ws + 64 * MB);  // 32MB
    _Float16* Kh  = (_Float16*)(ws + 96 * MB);  // 32MB
    _Float16* Vth = (_Float16*)(ws + 128 * MB); // 32MB
    // V in natural head layout goes to d_out as fp16 scratch (64MB buffer, 32MB used);
    // it is dead after transpose_v, and d_out is fully rewritten by the final GEMM.
    _Float16* Vn  = (_Float16*)d_out;

    cast_x_kernel<<<8192, 256, 0, stream>>>(x, xh);
    transpose_cast_w<<<dim3(64, 64, 4), dim3(32, 8), 0, stream>>>(
        Wq, Wk, Wv, Wo, wqt, wkt, wvt, wot);

    dim3 gg(64, 16); // (M/128, N/128)
    gemm_kernel<0><<<gg, 256, 0, stream>>>(xh, wqt, bq, Qh, MROWS, HDIM, HDIM);
    gemm_kernel<0><<<gg, 256, 0, stream>>>(xh, wkt, bk, Kh, MROWS, HDIM, HDIM);
    gemm_kernel<0><<<gg, 256, 0, stream>>>(xh, wvt, bv, Vn, MROWS, HDIM, HDIM);
    transpose_v<<<dim3(4, 64, 64), dim3(32, 8), 0, stream>>>(Vn, Vth);

    attn_kernel<<<dim3(16, 64), 256, 0, stream>>>(Qh, Kh, Vth, xh);

    gemm_kernel<2><<<gg, 256, 0, stream>>>(xh, wot, bo, d_out, MROWS, HDIM, HDIM);
}

// Round 8
// 1102.233 us; speedup vs baseline: 1.3102x; 1.3102x over previous
//
#include <hip/hip_runtime.h>

// Problem constants (fixed-size problem)
#define S_LEN 2048
#define HDIM  2048
#define NH    16
#define HD    128
#define MROWS 8192   // B*S

typedef __attribute__((ext_vector_type(8))) _Float16 half8;  // 8 x fp16 MFMA frag
typedef __attribute__((ext_vector_type(4))) float f32x4;     // MFMA accum

__device__ __forceinline__ _Float16 f2h(float f) { return (_Float16)f; }

// async global->LDS, 16B per lane. LDS dest must be wave-uniform base; HW adds lane*16.
// Global SOURCE address is per-lane (m104/m108) -> pre-swizzle source, keep LDS linear.
__device__ __forceinline__ void gload16(const void* g, void* l) {
    __builtin_amdgcn_global_load_lds(
        (const __attribute__((address_space(1))) void*)g,
        (__attribute__((address_space(3))) void*)l,
        16, 0, 0);
}

// ---------------------------------------------------------------- prep kernels
__global__ void cast_x_kernel(const float* __restrict__ x, _Float16* __restrict__ xh) {
    size_t i = ((size_t)blockIdx.x * 256 + threadIdx.x) * 8;
    float4 a = *(const float4*)(x + i);
    float4 b = *(const float4*)(x + i + 4);
    half8 o;
    o[0]=f2h(a.x); o[1]=f2h(a.y); o[2]=f2h(a.z); o[3]=f2h(a.w);
    o[4]=f2h(b.x); o[5]=f2h(b.y); o[6]=f2h(b.z); o[7]=f2h(b.w);
    *(half8*)(xh + i) = o;
}

// All four weights in one launch: W [K][N] fp32 -> Wt [N][K] fp16. blockIdx.z picks weight.
__global__ void transpose_cast_w(const float* W0, const float* W1,
                                 const float* W2, const float* W3,
                                 _Float16* T0, _Float16* T1,
                                 _Float16* T2, _Float16* T3) {
    __shared__ float t[32][33];
    const float* W = (blockIdx.z == 0) ? W0 : (blockIdx.z == 1) ? W1 : (blockIdx.z == 2) ? W2 : W3;
    _Float16*   Wt = (blockIdx.z == 0) ? T0 : (blockIdx.z == 1) ? T1 : (blockIdx.z == 2) ? T2 : T3;
    int x0 = blockIdx.x * 32, y0 = blockIdx.y * 32;  // x: N, y: K
    int tx = threadIdx.x, ty = threadIdx.y;          // (32,8)
    #pragma unroll
    for (int i = 0; i < 32; i += 8)
        t[ty + i][tx] = W[(size_t)(y0 + ty + i) * HDIM + x0 + tx];
    __syncthreads();
    #pragma unroll
    for (int i = 0; i < 32; i += 8)
        Wt[(size_t)(x0 + ty + i) * HDIM + y0 + tx] = f2h(t[tx][ty + i]);
}

// Per-head transpose: Vn [bh][S][HD] fp16 -> Vt [bh][HD][S] fp16.
__global__ void transpose_v(const _Float16* __restrict__ Vn, _Float16* __restrict__ Vt) {
    __shared__ _Float16 t[32][33];
    int d0 = blockIdx.x * 32, s0 = blockIdx.y * 32;
    size_t bh = blockIdx.z;
    const _Float16* src = Vn + bh * (size_t)S_LEN * HD;
    _Float16*       dst = Vt + bh * (size_t)S_LEN * HD;
    int tx = threadIdx.x, ty = threadIdx.y;          // (32,8)
    #pragma unroll
    for (int i = 0; i < 32; i += 8)
        t[ty + i][tx] = src[(size_t)(s0 + ty + i) * HD + d0 + tx];
    __syncthreads();
    #pragma unroll
    for (int i = 0; i < 32; i += 8)
        dst[(size_t)(d0 + ty + i) * S_LEN + s0 + tx] = t[tx][ty + i];
}

// ---------------------------------------------------------------- GEMM (m97 structure)
// C[M,N] = A[M,K](fp16) * Wt[N,K]^T(fp16) + bias, 128x128 tile, 4 waves (2x2), BK=32
// Grid is ALWAYS (64,16); T1 XCD swizzle assumes 1024 wgs (1024%8==0).
// MODE 0: write fp16 to [B][NH][S][HD]   (Q, K, V-natural)
// MODE 2: write fp32 to [M][N]           (final output)
template<int MODE>
__global__ __launch_bounds__(256, 2)
void gemm_kernel(const _Float16* __restrict__ A,
                 const _Float16* __restrict__ Bt,
                 const float* __restrict__ bias,
                 void* __restrict__ out,
                 int M, int N, int K)
{
    __shared__ _Float16 lA[128 * 32];
    __shared__ _Float16 lB[128 * 32];
    const int tid  = threadIdx.x;
    const int wave = tid >> 6;
    const int lane = tid & 63;
    const int fr = lane & 15, fq = lane >> 4;
    const int wr = wave >> 1, wc = wave & 1;

    const int f  = blockIdx.x + blockIdx.y * 64;   // flat wg id (1024 total)
    const int t  = (f & 7) * 128 + (f >> 3);
    const size_t m0 = (size_t)(t & 63) * 128;
    const size_t n0 = (size_t)(t >> 6) * 128;

    f32x4 acc[4][4] = {};

    for (int kt = 0; kt < K; kt += 32) {
        #pragma unroll
        for (int c = 0; c < 2; ++c) {
            int off  = (c * 4 + wave) * 1024 + lane * 16; // byte offset in 8KB tile
            int row  = off >> 6;                          // 64B per row (32 fp16)
            int colb = off & 63;
            gload16((const char*)A  + ((m0 + row) * K + kt) * 2 + colb,
                    (char*)lA + (c * 4 + wave) * 1024);
            gload16((const char*)Bt + ((n0 + row) * K + kt) * 2 + colb,
                    (char*)lB + (c * 4 + wave) * 1024);
        }
        __syncthreads();
        half8 a_[4], b_[4];
        #pragma unroll
        for (int m = 0; m < 4; ++m)
            a_[m] = *(const half8*)&lA[(wr * 64 + m * 16 + fr) * 32 + fq * 8];
        #pragma unroll
        for (int n = 0; n < 4; ++n)
            b_[n] = *(const half8*)&lB[(wc * 64 + n * 16 + fr) * 32 + fq * 8];
        #pragma unroll
        for (int m = 0; m < 4; ++m)
            #pragma unroll
            for (int n = 0; n < 4; ++n)
                acc[m][n] = __builtin_amdgcn_mfma_f32_16x16x32_f16(a_[m], b_[n], acc[m][n], 0, 0, 0);
        __syncthreads();
    }

    #pragma unroll
    for (int m = 0; m < 4; ++m) {
        #pragma unroll
        for (int n = 0; n < 4; ++n) {
            #pragma unroll
            for (int r = 0; r < 4; ++r) {
                size_t row = m0 + wr * 64 + m * 16 + fq * 4 + r;   // token index
                size_t col = n0 + wc * 64 + n * 16 + fr;           // output feature
                float v = acc[m][n][r] + bias[col];
                if (MODE == 0) {
                    size_t b = row >> 11, s = row & 2047;
                    size_t h = col >> 7,  d = col & 127;
                    ((_Float16*)out)[((b * NH + h) * S_LEN + s) * HD + d] = f2h(v);
                } else {
                    ((float*)out)[row * (size_t)N + col] = v;
                }
            }
        }
    }
}

// ---------------------------------------------------------------- attention v2
// grid (16,64), 4 waves/block, 128 q-rows/block (32/wave), KVBLK=64.
// K/V tiles cooperatively staged in LDS via gload16 (pre-swizzled source), single-buffered.
// LDS: lK 16KB + lV 16KB + lP 16KB = 48KB -> 3 blocks/CU target.
__global__ __launch_bounds__(256, 3)
void attn_kernel(const _Float16* __restrict__ Q,
                 const _Float16* __restrict__ K,
                 const _Float16* __restrict__ Vt,
                 _Float16* __restrict__ O)
{
    __shared__ _Float16 lK[64 * 128];    // [key][d], 256B rows, chunk-swizzled
    __shared__ _Float16 lV[128 * 64];    // [d][key], 128B rows, chunk-swizzled
    __shared__ _Float16 lP[4 * 32 * 64]; // per-wave 4KB, 128B rows, swizzled
    const int tid = threadIdx.x;
    const int wave = tid >> 6, lane = tid & 63;
    const int fr = lane & 15, fq = lane >> 4;

    // T1: XCD j gets heads [j*8,(j+1)*8), same-head q-blocks consecutive.
    const int f  = blockIdx.x + blockIdx.y * 16;   // flat wg id (1024 total)
    const int t  = (f & 7) * 128 + (f >> 3);
    const int bh = t >> 4;
    const int q0 = (t & 15) * 128 + wave * 32;

    const _Float16* Qh = Q  + (size_t)bh * S_LEN * HD;
    const _Float16* Kh = K  + (size_t)bh * S_LEN * HD;
    const _Float16* Vh = Vt + (size_t)bh * HD * S_LEN;
    _Float16* pw = lP + wave * 32 * 64;

    // Q fragments resident in registers, pre-scaled by 1/sqrt(hd).
    const _Float16 hscale = (_Float16)0.08838834764831845f;  // 1/sqrt(128)
    half8 qf[2][4];
    #pragma unroll
    for (int m = 0; m < 2; ++m)
        #pragma unroll
        for (int kk = 0; kk < 4; ++kk) {
            half8 t_ = *(const half8*)&Qh[(size_t)(q0 + m * 16 + fr) * HD + kk * 32 + fq * 8];
            qf[m][kk] = t_ * hscale;
        }

    f32x4 acc_o[2][8] = {};
    float m_run[2][4], l_run[2][4];
    #pragma unroll
    for (int m = 0; m < 2; ++m)
        #pragma unroll
        for (int r = 0; r < 4; ++r) { m_run[m][r] = -1e30f; l_run[m][r] = 0.f; }

    for (int kt = 0; kt < S_LEN; kt += 64) {
        __syncthreads();   // all waves done reading previous K/V tile
        // ---- stage K tile [64 key rows][128 d] = 16KB; 16 chunks/row.
        // LDS chunk g holds global chunk (g&15)^(row&7) of row g>>4  (rule 21 pair).
        #pragma unroll
        for (int i = 0; i < 4; ++i) {
            int g   = i * 256 + tid;
            int row = g >> 4;
            int c   = (g & 15) ^ (row & 7);
            gload16((const char*)Kh + ((size_t)(kt + row) * HD) * 2 + c * 16,
                    (char*)lK + (i * 4 + wave) * 1024);
        }
        // ---- stage V tile [128 d rows][64 key] = 16KB; 8 chunks/row.
        #pragma unroll
        for (int i = 0; i < 4; ++i) {
            int g   = i * 256 + tid;
            int row = g >> 3;
            int c   = (g & 7) ^ (row & 7);
            gload16((const char*)Vh + ((size_t)row * S_LEN + kt) * 2 + c * 16,
                    (char*)lV + (i * 4 + wave) * 1024);
        }
        __syncthreads();   // implies vmcnt(0) drain -> tile fully staged

        // ---- S = (Q/sqrt(hd)) K^T  (keys n*16+fr, n<4)
        f32x4 acc_s[2][4] = {};
        #pragma unroll
        for (int kk = 0; kk < 4; ++kk) {
            half8 kf[4];
            #pragma unroll
            for (int n = 0; n < 4; ++n) {
                int row = n * 16 + fr;
                int off = row * 256 + (((kk * 4 + fq) ^ (row & 7)) * 16);
                kf[n] = *(const half8*)((const char*)lK + off);
            }
            __builtin_amdgcn_s_setprio(1);
            #pragma unroll
            for (int m = 0; m < 2; ++m)
                #pragma unroll
                for (int n = 0; n < 4; ++n)
                    acc_s[m][n] = __builtin_amdgcn_mfma_f32_16x16x32_f16(qf[m][kk], kf[n], acc_s[m][n], 0, 0, 0);
            __builtin_amdgcn_s_setprio(0);
        }
        // ---- online softmax (rows m*16+fq*4+r; reduce over 4 regs + 16 fr lanes)
        #pragma unroll
        for (int m = 0; m < 2; ++m) {
            #pragma unroll
            for (int r = 0; r < 4; ++r) {
                float rowmax = acc_s[m][0][r];
                #pragma unroll
                for (int n = 1; n < 4; ++n)
                    rowmax = fmaxf(rowmax, acc_s[m][n][r]);
                rowmax = fmaxf(rowmax, __shfl_xor(rowmax, 1));
                rowmax = fmaxf(rowmax, __shfl_xor(rowmax, 2));
                rowmax = fmaxf(rowmax, __shfl_xor(rowmax, 4));
                rowmax = fmaxf(rowmax, __shfl_xor(rowmax, 8));
                // T13 defer-max
                float mold = m_run[m][r];
                if (rowmax > mold + 8.f) {
                    float fac = __expf(mold - rowmax);
                    m_run[m][r] = rowmax;
                    l_run[m][r] *= fac;
                    #pragma unroll
                    for (int n = 0; n < 8; ++n)
                        acc_o[m][n][r] *= fac;
                }
                float mcur = m_run[m][r];
                float rowsum = 0.f;
                #pragma unroll
                for (int n = 0; n < 4; ++n) {
                    float p = __expf(acc_s[m][n][r] - mcur);
                    acc_s[m][n][r] = p;
                    rowsum += p;
                }
                rowsum += __shfl_xor(rowsum, 1);
                rowsum += __shfl_xor(rowsum, 2);
                rowsum += __shfl_xor(rowsum, 4);
                rowsum += __shfl_xor(rowsum, 8);
                l_run[m][r] += rowsum;
            }
        }
        // ---- P -> per-wave LDS (rows 128B, chunk-swizzled by (row&7)<<4)
        #pragma unroll
        for (int m = 0; m < 2; ++m)
            #pragma unroll
            for (int n = 0; n < 4; ++n)
                #pragma unroll
                for (int r = 0; r < 4; ++r) {
                    int row = m * 16 + fq * 4 + r;
                    int off = row * 128 + (((n * 16 + fr) * 2) ^ ((row & 7) << 4));
                    *(_Float16*)((char*)pw + off) = f2h(acc_s[m][n][r]);
                }
        asm volatile("s_waitcnt lgkmcnt(0)" ::: "memory");
        __builtin_amdgcn_sched_barrier(0);
        // ---- O += P V   (kk<2 over KVBLK=64)
        #pragma unroll
        for (int kk = 0; kk < 2; ++kk) {
            half8 pf[2], vf[8];
            #pragma unroll
            for (int m = 0; m < 2; ++m) {
                int row = m * 16 + fr;
                int off = row * 128 + ((kk * 64 + fq * 16) ^ ((row & 7) << 4));
                pf[m] = *(const half8*)((const char*)pw + off);
            }
            #pragma unroll
            for (int n = 0; n < 8; ++n) {
                int row = n * 16 + fr;
                int off = row * 128 + (((kk * 4 + fq) ^ (row & 7)) * 16);
                vf[n] = *(const half8*)((const char*)lV + off);
            }
            __builtin_amdgcn_s_setprio(1);
            #pragma unroll
            for (int m = 0; m < 2; ++m)
                #pragma unroll
                for (int n = 0; n < 8; ++n)
                    acc_o[m][n] = __builtin_amdgcn_mfma_f32_16x16x32_f16(pf[m], vf[n], acc_o[m][n], 0, 0, 0);
            __builtin_amdgcn_s_setprio(0);
        }
    }

    // ---- epilogue: O / l, write fp16 [token][h*128+d]
    const int b = bh >> 4, h = bh & 15;
    #pragma unroll
    for (int m = 0; m < 2; ++m) {
        #pragma unroll
        for (int r = 0; r < 4; ++r) {
            float inv = 1.f / l_run[m][r];
            size_t tok = (size_t)b * S_LEN + q0 + m * 16 + fq * 4 + r;
            #pragma unroll
            for (int n = 0; n < 8; ++n) {
                size_t col = (size_t)h * HD + n * 16 + fr;
                O[tok * HDIM + col] = f2h(acc_o[m][n][r] * inv);
            }
        }
    }
}

// ---------------------------------------------------------------- launch
extern "C" void kernel_launch(void* const* d_in, const int* in_sizes, int n_in,
                              void* d_out, int out_size, void* d_ws, size_t ws_size,
                              hipStream_t stream)
{
    (void)in_sizes; (void)n_in; (void)out_size; (void)ws_size;
    const float* x  = (const float*)d_in[0];
    const float* Wq = (const float*)d_in[1];
    const float* bq = (const float*)d_in[2];
    const float* Wk = (const float*)d_in[3];
    const float* bk = (const float*)d_in[4];
    const float* Wv = (const float*)d_in[5];
    const float* bv = (const float*)d_in[6];
    const float* Wo = (const float*)d_in[7];
    const float* bo = (const float*)d_in[8];

    const size_t MB = 1024ull * 1024ull;
    char* ws = (char*)d_ws;
    _Float16* xh  = (_Float16*)(ws);            // 32MB: x fp16; reused as attn out
    _Float16* wqt = (_Float16*)(ws + 32 * MB);  // 8MB each
    _Float16* wkt = (_Float16*)(ws + 40 * MB);
    _Float16* wvt = (_Float16*)(ws + 48 * MB);
    _Float16* wot = (_Float16*)(ws + 56 * MB);
    _Float16* Qh  = (_Float16*)(ws + 64 * MB);  // 32MB
    _Float16* Kh  = (_Float16*)(ws + 96 * MB);  // 32MB
    _Float16* Vth = (_Float16*)(ws + 128 * MB); // 32MB
    // V natural-layout scratch lives in d_out (dead after transpose_v; d_out rewritten by final GEMM)
    _Float16* Vn  = (_Float16*)d_out;

    cast_x_kernel<<<8192, 256, 0, stream>>>(x, xh);
    transpose_cast_w<<<dim3(64, 64, 4), dim3(32, 8), 0, stream>>>(
        Wq, Wk, Wv, Wo, wqt, wkt, wvt, wot);

    dim3 gg(64, 16); // (M/128, N/128)
    gemm_kernel<0><<<gg, 256, 0, stream>>>(xh, wqt, bq, Qh, MROWS, HDIM, HDIM);
    gemm_kernel<0><<<gg, 256, 0, stream>>>(xh, wkt, bk, Kh, MROWS, HDIM, HDIM);
    gemm_kernel<0><<<gg, 256, 0, stream>>>(xh, wvt, bv, Vn, MROWS, HDIM, HDIM);
    transpose_v<<<dim3(4, 64, 64), dim3(32, 8), 0, stream>>>(Vn, Vth);

    attn_kernel<<<dim3(16, 64), 256, 0, stream>>>(Qh, Kh, Vth, xh);

    gemm_kernel<2><<<gg, 256, 0, stream>>>(xh, wot, bo, d_out, MROWS, HDIM, HDIM);
}

// Round 9
// 820.957 us; speedup vs baseline: 1.7591x; 1.3426x over previous
//
#include <hip/hip_runtime.h>

// Problem constants (fixed-size problem)
#define S_LEN 2048
#define HDIM  2048
#define NH    16
#define HD    128
#define MROWS 8192   // B*S

typedef __attribute__((ext_vector_type(8))) _Float16 half8;  // 8 x fp16 MFMA frag
typedef __attribute__((ext_vector_type(4))) float f32x4;     // MFMA accum

__device__ __forceinline__ _Float16 f2h(float f) { return (_Float16)f; }

// async global->LDS, 16B per lane. LDS dest must be wave-uniform base; HW adds lane*16.
// Global SOURCE address is per-lane (m104/m108) -> pre-swizzle source, keep LDS linear.
__device__ __forceinline__ void gload16(const void* g, void* l) {
    __builtin_amdgcn_global_load_lds(
        (const __attribute__((address_space(1))) void*)g,
        (__attribute__((address_space(3))) void*)l,
        16, 0, 0);
}

// ---------------------------------------------------------------- prep kernels
__global__ void cast_x_kernel(const float* __restrict__ x, _Float16* __restrict__ xh) {
    size_t i = ((size_t)blockIdx.x * 256 + threadIdx.x) * 8;
    float4 a = *(const float4*)(x + i);
    float4 b = *(const float4*)(x + i + 4);
    half8 o;
    o[0]=f2h(a.x); o[1]=f2h(a.y); o[2]=f2h(a.z); o[3]=f2h(a.w);
    o[4]=f2h(b.x); o[5]=f2h(b.y); o[6]=f2h(b.z); o[7]=f2h(b.w);
    *(half8*)(xh + i) = o;
}

// All four weights in one launch: W [K][N] fp32 -> Wt [N][K] fp16. blockIdx.z picks weight.
__global__ void transpose_cast_w(const float* W0, const float* W1,
                                 const float* W2, const float* W3,
                                 _Float16* T0, _Float16* T1,
                                 _Float16* T2, _Float16* T3) {
    __shared__ float t[32][33];
    const float* W = (blockIdx.z == 0) ? W0 : (blockIdx.z == 1) ? W1 : (blockIdx.z == 2) ? W2 : W3;
    _Float16*   Wt = (blockIdx.z == 0) ? T0 : (blockIdx.z == 1) ? T1 : (blockIdx.z == 2) ? T2 : T3;
    int x0 = blockIdx.x * 32, y0 = blockIdx.y * 32;  // x: N, y: K
    int tx = threadIdx.x, ty = threadIdx.y;          // (32,8)
    #pragma unroll
    for (int i = 0; i < 32; i += 8)
        t[ty + i][tx] = W[(size_t)(y0 + ty + i) * HDIM + x0 + tx];
    __syncthreads();
    #pragma unroll
    for (int i = 0; i < 32; i += 8)
        Wt[(size_t)(x0 + ty + i) * HDIM + y0 + tx] = f2h(t[tx][ty + i]);
}

// Per-head transpose: Vn [bh][S][HD] fp16 -> Vt [bh][HD][S] fp16.
__global__ void transpose_v(const _Float16* __restrict__ Vn, _Float16* __restrict__ Vt) {
    __shared__ _Float16 t[32][33];
    int d0 = blockIdx.x * 32, s0 = blockIdx.y * 32;
    size_t bh = blockIdx.z;
    const _Float16* src = Vn + bh * (size_t)S_LEN * HD;
    _Float16*       dst = Vt + bh * (size_t)S_LEN * HD;
    int tx = threadIdx.x, ty = threadIdx.y;          // (32,8)
    #pragma unroll
    for (int i = 0; i < 32; i += 8)
        t[ty + i][tx] = src[(size_t)(s0 + ty + i) * HD + d0 + tx];
    __syncthreads();
    #pragma unroll
    for (int i = 0; i < 32; i += 8)
        dst[(size_t)(d0 + ty + i) * S_LEN + s0 + tx] = t[tx][ty + i];
}

// ---------------------------------------------------------------- GEMM (m97 structure)
// C[M,N] = A[M,K](fp16) * Wt[N,K]^T(fp16) + bias, 128x128 tile, 4 waves (2x2), BK=32
// Grid is ALWAYS (64,16); T1 XCD swizzle assumes 1024 wgs (1024%8==0).
// MODE 0: write fp16 to [B][NH][S][HD]   (Q, K, V-natural)
// MODE 2: write fp32 to [M][N]           (final output)
template<int MODE>
__global__ __launch_bounds__(256, 2)
void gemm_kernel(const _Float16* __restrict__ A,
                 const _Float16* __restrict__ Bt,
                 const float* __restrict__ bias,
                 void* __restrict__ out,
                 int M, int N, int K)
{
    __shared__ _Float16 lA[128 * 32];
    __shared__ _Float16 lB[128 * 32];
    const int tid  = threadIdx.x;
    const int wave = tid >> 6;
    const int lane = tid & 63;
    const int fr = lane & 15, fq = lane >> 4;
    const int wr = wave >> 1, wc = wave & 1;

    const int f  = blockIdx.x + blockIdx.y * 64;   // flat wg id (1024 total)
    const int t  = (f & 7) * 128 + (f >> 3);
    const size_t m0 = (size_t)(t & 63) * 128;
    const size_t n0 = (size_t)(t >> 6) * 128;

    f32x4 acc[4][4] = {};

    for (int kt = 0; kt < K; kt += 32) {
        #pragma unroll
        for (int c = 0; c < 2; ++c) {
            int off  = (c * 4 + wave) * 1024 + lane * 16; // byte offset in 8KB tile
            int row  = off >> 6;                          // 64B per row (32 fp16)
            int colb = off & 63;
            gload16((const char*)A  + ((m0 + row) * K + kt) * 2 + colb,
                    (char*)lA + (c * 4 + wave) * 1024);
            gload16((const char*)Bt + ((n0 + row) * K + kt) * 2 + colb,
                    (char*)lB + (c * 4 + wave) * 1024);
        }
        __syncthreads();
        half8 a_[4], b_[4];
        #pragma unroll
        for (int m = 0; m < 4; ++m)
            a_[m] = *(const half8*)&lA[(wr * 64 + m * 16 + fr) * 32 + fq * 8];
        #pragma unroll
        for (int n = 0; n < 4; ++n)
            b_[n] = *(const half8*)&lB[(wc * 64 + n * 16 + fr) * 32 + fq * 8];
        #pragma unroll
        for (int m = 0; m < 4; ++m)
            #pragma unroll
            for (int n = 0; n < 4; ++n)
                acc[m][n] = __builtin_amdgcn_mfma_f32_16x16x32_f16(a_[m], b_[n], acc[m][n], 0, 0, 0);
        __syncthreads();
    }

    #pragma unroll
    for (int m = 0; m < 4; ++m) {
        #pragma unroll
        for (int n = 0; n < 4; ++n) {
            #pragma unroll
            for (int r = 0; r < 4; ++r) {
                size_t row = m0 + wr * 64 + m * 16 + fq * 4 + r;   // token index
                size_t col = n0 + wc * 64 + n * 16 + fr;           // output feature
                float v = acc[m][n][r] + bias[col];
                if (MODE == 0) {
                    size_t b = row >> 11, s = row & 2047;
                    size_t h = col >> 7,  d = col & 127;
                    ((_Float16*)out)[((b * NH + h) * S_LEN + s) * HD + d] = f2h(v);
                } else {
                    ((float*)out)[row * (size_t)N + col] = v;
                }
            }
        }
    }
}

// ---------------------------------------------------------------- attention v3
// grid (16,64), 4 waves/block, 128 q-rows/block (32/wave), KVBLK=64.
// T3 2-phase pipeline: STAGE(t+1) into buf^1 issued BEFORE compute(t); the implicit
// vmcnt(0) drain in the single end-of-tile __syncthreads() lands after compute, so
// next-tile HBM/L2 latency hides under QK^T+softmax+PV. LDS: 2*16K (K) + 2*16K (V)
// + 16K (P) = 80KB -> 2 blocks/CU.
__global__ __launch_bounds__(256, 2)
void attn_kernel(const _Float16* __restrict__ Q,
                 const _Float16* __restrict__ K,
                 const _Float16* __restrict__ Vt,
                 _Float16* __restrict__ O)
{
    __shared__ _Float16 lK[2 * 64 * 128];   // [buf][key][d], 256B rows, chunk-swizzled
    __shared__ _Float16 lV[2 * 128 * 64];   // [buf][d][key], 128B rows, chunk-swizzled
    __shared__ _Float16 lP[4 * 32 * 64];    // per-wave 4KB, 128B rows, swizzled
    const int tid = threadIdx.x;
    const int wave = tid >> 6, lane = tid & 63;
    const int fr = lane & 15, fq = lane >> 4;

    // T1: XCD j gets heads [j*8,(j+1)*8), same-head q-blocks consecutive.
    const int f  = blockIdx.x + blockIdx.y * 16;   // flat wg id (1024 total)
    const int t_ = (f & 7) * 128 + (f >> 3);
    const int bh = t_ >> 4;
    const int q0 = (t_ & 15) * 128 + wave * 32;

    const _Float16* Qh = Q  + (size_t)bh * S_LEN * HD;
    const _Float16* Kh = K  + (size_t)bh * S_LEN * HD;
    const _Float16* Vh = Vt + (size_t)bh * HD * S_LEN;
    _Float16* pw = lP + wave * 32 * 64;

    // cooperative stage of one KV tile (8 gload16/thread; rule-21 pre-swizzled source)
    auto stage = [&](int buf, int kt) {
        char* kb = (char*)(lK + buf * (64 * 128));
        char* vb = (char*)(lV + buf * (128 * 64));
        #pragma unroll
        for (int i = 0; i < 4; ++i) {
            int g   = i * 256 + tid;
            int row = g >> 4;
            int c   = (g & 15) ^ (row & 7);
            gload16((const char*)Kh + ((size_t)(kt + row) * HD) * 2 + c * 16,
                    kb + (i * 4 + wave) * 1024);
        }
        #pragma unroll
        for (int i = 0; i < 4; ++i) {
            int g   = i * 256 + tid;
            int row = g >> 3;
            int c   = (g & 7) ^ (row & 7);
            gload16((const char*)Vh + ((size_t)row * S_LEN + kt) * 2 + c * 16,
                    vb + (i * 4 + wave) * 1024);
        }
    };

    // Q fragments resident in registers, pre-scaled by 1/sqrt(hd).
    const _Float16 hscale = (_Float16)0.08838834764831845f;  // 1/sqrt(128)
    half8 qf[2][4];
    #pragma unroll
    for (int m = 0; m < 2; ++m)
        #pragma unroll
        for (int kk = 0; kk < 4; ++kk) {
            half8 tq = *(const half8*)&Qh[(size_t)(q0 + m * 16 + fr) * HD + kk * 32 + fq * 8];
            qf[m][kk] = tq * hscale;
        }

    f32x4 acc_o[2][8] = {};
    float m_run[2][4], l_run[2][4];
    #pragma unroll
    for (int m = 0; m < 2; ++m)
        #pragma unroll
        for (int r = 0; r < 4; ++r) { m_run[m][r] = -1e30f; l_run[m][r] = 0.f; }

    stage(0, 0);
    __syncthreads();   // drains vmcnt -> tile 0 staged

    int cur = 0;
    for (int t = 0; t < S_LEN / 64; ++t) {
        if (t < S_LEN / 64 - 1) stage(cur ^ 1, (t + 1) * 64);   // prefetch under compute
        const char* kb = (const char*)(lK + cur * (64 * 128));
        const char* vb = (const char*)(lV + cur * (128 * 64));

        // ---- S = (Q/sqrt(hd)) K^T  (keys n*16+fr, n<4)
        f32x4 acc_s[2][4] = {};
        #pragma unroll
        for (int kk = 0; kk < 4; ++kk) {
            half8 kf[4];
            #pragma unroll
            for (int n = 0; n < 4; ++n) {
                int row = n * 16 + fr;
                int off = row * 256 + (((kk * 4 + fq) ^ (row & 7)) * 16);
                kf[n] = *(const half8*)(kb + off);
            }
            __builtin_amdgcn_s_setprio(1);
            #pragma unroll
            for (int m = 0; m < 2; ++m)
                #pragma unroll
                for (int n = 0; n < 4; ++n)
                    acc_s[m][n] = __builtin_amdgcn_mfma_f32_16x16x32_f16(qf[m][kk], kf[n], acc_s[m][n], 0, 0, 0);
            __builtin_amdgcn_s_setprio(0);
        }
        // ---- online softmax (rows m*16+fq*4+r; reduce over 4 regs + 16 fr lanes)
        #pragma unroll
        for (int m = 0; m < 2; ++m) {
            #pragma unroll
            for (int r = 0; r < 4; ++r) {
                float rowmax = acc_s[m][0][r];
                #pragma unroll
                for (int n = 1; n < 4; ++n)
                    rowmax = fmaxf(rowmax, acc_s[m][n][r]);
                rowmax = fmaxf(rowmax, __shfl_xor(rowmax, 1));
                rowmax = fmaxf(rowmax, __shfl_xor(rowmax, 2));
                rowmax = fmaxf(rowmax, __shfl_xor(rowmax, 4));
                rowmax = fmaxf(rowmax, __shfl_xor(rowmax, 8));
                // T13 defer-max
                float mold = m_run[m][r];
                if (rowmax > mold + 8.f) {
                    float fac = __expf(mold - rowmax);
                    m_run[m][r] = rowmax;
                    l_run[m][r] *= fac;
                    #pragma unroll
                    for (int n = 0; n < 8; ++n)
                        acc_o[m][n][r] *= fac;
                }
                float mcur = m_run[m][r];
                float rowsum = 0.f;
                #pragma unroll
                for (int n = 0; n < 4; ++n) {
                    float p = __expf(acc_s[m][n][r] - mcur);
                    acc_s[m][n][r] = p;
                    rowsum += p;
                }
                rowsum += __shfl_xor(rowsum, 1);
                rowsum += __shfl_xor(rowsum, 2);
                rowsum += __shfl_xor(rowsum, 4);
                rowsum += __shfl_xor(rowsum, 8);
                l_run[m][r] += rowsum;
            }
        }
        // ---- P -> per-wave LDS (rows 128B, chunk-swizzled by (row&7)<<4)
        #pragma unroll
        for (int m = 0; m < 2; ++m)
            #pragma unroll
            for (int n = 0; n < 4; ++n)
                #pragma unroll
                for (int r = 0; r < 4; ++r) {
                    int row = m * 16 + fq * 4 + r;
                    int off = row * 128 + (((n * 16 + fr) * 2) ^ ((row & 7) << 4));
                    *(_Float16*)((char*)pw + off) = f2h(acc_s[m][n][r]);
                }
        asm volatile("s_waitcnt lgkmcnt(0)" ::: "memory");
        __builtin_amdgcn_sched_barrier(0);
        // ---- O += P V   (kk<2 over KVBLK=64)
        #pragma unroll
        for (int kk = 0; kk < 2; ++kk) {
            half8 pf[2], vf[8];
            #pragma unroll
            for (int m = 0; m < 2; ++m) {
                int row = m * 16 + fr;
                int off = row * 128 + ((kk * 64 + fq * 16) ^ ((row & 7) << 4));
                pf[m] = *(const half8*)((const char*)pw + off);
            }
            #pragma unroll
            for (int n = 0; n < 8; ++n) {
                int row = n * 16 + fr;
                int off = row * 128 + (((kk * 4 + fq) ^ (row & 7)) * 16);
                vf[n] = *(const half8*)(vb + off);
            }
            __builtin_amdgcn_s_setprio(1);
            #pragma unroll
            for (int m = 0; m < 2; ++m)
                #pragma unroll
                for (int n = 0; n < 8; ++n)
                    acc_o[m][n] = __builtin_amdgcn_mfma_f32_16x16x32_f16(pf[m], vf[n], acc_o[m][n], 0, 0, 0);
            __builtin_amdgcn_s_setprio(0);
        }
        __syncthreads();   // single barrier/tile; implicit vmcnt(0) covers prefetch
        cur ^= 1;
    }

    // ---- epilogue: O / l, write fp16 [token][h*128+d]
    const int b = bh >> 4, h = bh & 15;
    #pragma unroll
    for (int m = 0; m < 2; ++m) {
        #pragma unroll
        for (int r = 0; r < 4; ++r) {
            float inv = 1.f / l_run[m][r];
            size_t tok = (size_t)b * S_LEN + q0 + m * 16 + fq * 4 + r;
            #pragma unroll
            for (int n = 0; n < 8; ++n) {
                size_t col = (size_t)h * HD + n * 16 + fr;
                O[tok * HDIM + col] = f2h(acc_o[m][n][r] * inv);
            }
        }
    }
}

// ---------------------------------------------------------------- launch
extern "C" void kernel_launch(void* const* d_in, const int* in_sizes, int n_in,
                              void* d_out, int out_size, void* d_ws, size_t ws_size,
                              hipStream_t stream)
{
    (void)in_sizes; (void)n_in; (void)out_size; (void)ws_size;
    const float* x  = (const float*)d_in[0];
    const float* Wq = (const float*)d_in[1];
    const float* bq = (const float*)d_in[2];
    const float* Wk = (const float*)d_in[3];
    const float* bk = (const float*)d_in[4];
    const float* Wv = (const float*)d_in[5];
    const float* bv = (const float*)d_in[6];
    const float* Wo = (const float*)d_in[7];
    const float* bo = (const float*)d_in[8];

    const size_t MB = 1024ull * 1024ull;
    char* ws = (char*)d_ws;
    _Float16* xh  = (_Float16*)(ws);            // 32MB: x fp16; reused as attn out
    _Float16* wqt = (_Float16*)(ws + 32 * MB);  // 8MB each
    _Float16* wkt = (_Float16*)(ws + 40 * MB);
    _Float16* wvt = (_Float16*)(ws + 48 * MB);
    _Float16* wot = (_Float16*)(ws + 56 * MB);
    _Float16* Qh  = (_Float16*)(ws + 64 * MB);  // 32MB
    _Float16* Kh  = (_Float16*)(ws + 96 * MB);  // 32MB
    _Float16* Vth = (_Float16*)(ws + 128 * MB); // 32MB
    // V natural-layout scratch lives in d_out (dead after transpose_v; d_out rewritten by final GEMM)
    _Float16* Vn  = (_Float16*)d_out;

    cast_x_kernel<<<8192, 256, 0, stream>>>(x, xh);
    transpose_cast_w<<<dim3(64, 64, 4), dim3(32, 8), 0, stream>>>(
        Wq, Wk, Wv, Wo, wqt, wkt, wvt, wot);

    dim3 gg(64, 16); // (M/128, N/128)
    gemm_kernel<0><<<gg, 256, 0, stream>>>(xh, wqt, bq, Qh, MROWS, HDIM, HDIM);
    gemm_kernel<0><<<gg, 256, 0, stream>>>(xh, wkt, bk, Kh, MROWS, HDIM, HDIM);
    gemm_kernel<0><<<gg, 256, 0, stream>>>(xh, wvt, bv, Vn, MROWS, HDIM, HDIM);
    transpose_v<<<dim3(4, 64, 64), dim3(32, 8), 0, stream>>>(Vn, Vth);

    attn_kernel<<<dim3(16, 64), 256, 0, stream>>>(Qh, Kh, Vth, xh);

    gemm_kernel<2><<<gg, 256, 0, stream>>>(xh, wot, bo, d_out, MROWS, HDIM, HDIM);
}